// Round 1
// baseline (8947.194 us; speedup 1.0000x reference)
//
#include <hip/hip_runtime.h>

#define F 128          // feature dim (IN_DIM == HID == 128)
#define F4 32          // feature dim in float4

// ---------- degree / normalization ----------
__global__ void k_init_deg(float* deg, int n) {
    int i = blockIdx.x * blockDim.x + threadIdx.x;
    if (i < n) deg[i] = 1.0f;   // self-loop
}

__global__ void k_count(const int* __restrict__ dst, float* deg, int e) {
    int i = blockIdx.x * blockDim.x + threadIdx.x;
    if (i < e) atomicAdd(&deg[dst[i]], 1.0f);
}

__global__ void k_rsqrt(float* deg, int n) {
    int i = blockIdx.x * blockDim.x + threadIdx.x;
    if (i < n) deg[i] = 1.0f / sqrtf(deg[i]);   // accurate rsqrt
}

// ---------- dense matmul: H[n,128] = X[n,128] @ W[128,128] ----------
// one block per row, 128 threads; X row staged in LDS, W streamed (L2-resident)
__global__ void k_matmul(const float* __restrict__ X, const float* __restrict__ W,
                         float* __restrict__ H, int n) {
    int row = blockIdx.x;
    int j = threadIdx.x;
    __shared__ float xs[F];
    xs[j] = X[(size_t)row * F + j];
    __syncthreads();
    float acc = 0.f;
#pragma unroll
    for (int k = 0; k < F; ++k)
        acc = fmaf(xs[k], W[k * F + j], acc);
    H[(size_t)row * F + j] = acc;
}

// ---------- self-loop term initializes the aggregation buffer ----------
// agg[v,:] = h[v,:] * dinv[v]^2
__global__ void k_selfloop(const float4* __restrict__ H, const float* __restrict__ dinv,
                           float4* __restrict__ agg, int n) {
    int i = blockIdx.x * blockDim.x + threadIdx.x;   // over n*32
    if (i < n * F4) {
        int node = i >> 5;
        float d = dinv[node];
        d = d * d;
        float4 v = H[i];
        v.x *= d; v.y *= d; v.z *= d; v.w *= d;
        agg[i] = v;
    }
}

// ---------- edge scatter: agg[dst,:] += h[src,:] * dinv[src]*dinv[dst] ----------
// 32 threads per edge, float4 gather + 4 scalar atomic adds
__global__ void k_scatter(const float* __restrict__ H, const int* __restrict__ src,
                          const int* __restrict__ dst, const float* __restrict__ dinv,
                          float* agg, int e) {
    int t = blockIdx.x * blockDim.x + threadIdx.x;
    int edge = t >> 5;
    int lane = t & 31;
    if (edge >= e) return;
    int s = src[edge];
    int d = dst[edge];
    float norm = dinv[s] * dinv[d];
    float4 v = ((const float4*)(H + (size_t)s * F))[lane];
    float* a = agg + (size_t)d * F + lane * 4;
    atomicAdd(a + 0, v.x * norm);
    atomicAdd(a + 1, v.y * norm);
    atomicAdd(a + 2, v.z * norm);
    atomicAdd(a + 3, v.w * norm);
}

// ---------- fused bias + relu (in place) ----------
__global__ void k_bias_relu(float4* agg, const float4* __restrict__ b, int n) {
    int i = blockIdx.x * blockDim.x + threadIdx.x;   // over n*32
    if (i < n * F4) {
        float4 v = agg[i];
        float4 bb = b[i & (F4 - 1)];
        v.x = fmaxf(v.x + bb.x, 0.f);
        v.y = fmaxf(v.y + bb.y, 0.f);
        v.z = fmaxf(v.z + bb.z, 0.f);
        v.w = fmaxf(v.w + bb.w, 0.f);
        agg[i] = v;
    }
}

// ---------- mean pool ----------
__global__ void k_zero128(float* p) {
    p[threadIdx.x] = 0.f;
}

__global__ void k_pool(const float* __restrict__ H, float* pooled, int n, float inv_n) {
    // 256 threads: 2 rows per iteration, feature = tid & 127 (coalesced 1KB reads)
    int f = threadIdx.x & (F - 1);
    int rowoff = threadIdx.x >> 7;   // 0 or 1
    float s = 0.f;
    for (int row = blockIdx.x * 2 + rowoff; row < n; row += gridDim.x * 2)
        s += H[(size_t)row * F + f];
    __shared__ float sm[256];
    sm[threadIdx.x] = s;
    __syncthreads();
    if (threadIdx.x < F) {
        float v = sm[threadIdx.x] + sm[threadIdx.x + F];
        atomicAdd(&pooled[f], v * inv_n);
    }
}

// ---------- final FC: out[1,2] = pooled @ fc_w + fc_b ----------
__global__ void k_fc(const float* __restrict__ pooled, const float* __restrict__ fcw,
                     const float* __restrict__ fcb, float* out) {
    __shared__ float sm[2 * F];
    int f = threadIdx.x;   // 0..127
    float p = pooled[f];
    sm[f]       = p * fcw[f * 2 + 0];
    sm[f + F]   = p * fcw[f * 2 + 1];
    __syncthreads();
    for (int off = 64; off > 0; off >>= 1) {
        if (f < off) {
            sm[f]     += sm[f + off];
            sm[F + f] += sm[F + f + off];
        }
        __syncthreads();
    }
    if (f == 0) {
        out[0] = sm[0] + fcb[0];
        out[1] = sm[F] + fcb[1];
    }
}

extern "C" void kernel_launch(void* const* d_in, const int* in_sizes, int n_in,
                              void* d_out, int out_size, void* d_ws, size_t ws_size,
                              hipStream_t stream) {
    const float* x   = (const float*)d_in[0];
    const int*   ei  = (const int*)  d_in[1];
    const float* W1  = (const float*)d_in[2];
    const float* b1  = (const float*)d_in[3];
    const float* W2  = (const float*)d_in[4];
    const float* b2  = (const float*)d_in[5];
    const float* W3  = (const float*)d_in[6];
    const float* b3  = (const float*)d_in[7];
    const float* fcw = (const float*)d_in[8];
    const float* fcb = (const float*)d_in[9];
    float* out = (float*)d_out;

    const int n = in_sizes[0] / F;     // 100000
    const int e = in_sizes[1] / 2;     // 1600000
    const int* src = ei;
    const int* dst = ei + e;

    // workspace layout (floats): dinv[n] | pooled[128] | bufA[n*128] | bufB[n*128]
    float* ws     = (float*)d_ws;
    float* dinv   = ws;
    float* pooled = ws + (((size_t)n + 255) & ~(size_t)255);
    float* bufA   = pooled + 256;
    float* bufB   = bufA + (size_t)n * F;

    const int BT = 256;
    dim3 blk(BT);
    int gN   = (n + BT - 1) / BT;
    int gE   = (e + BT - 1) / BT;
    int gNF4 = (n * F4 + BT - 1) / BT;
    int gE32 = ((e * 32) + BT - 1) / BT;   // 32 threads per edge

    // normalization
    k_init_deg<<<gN, blk, 0, stream>>>(dinv, n);
    k_count   <<<gE, blk, 0, stream>>>(dst, dinv, e);
    k_rsqrt   <<<gN, blk, 0, stream>>>(dinv, n);

    const float* layer_in = x;
    const float* Ws[3] = {W1, W2, W3};
    const float* bs[3] = {b1, b2, b3};

    for (int l = 0; l < 3; ++l) {
        // M = layer_in @ W   (into bufB)
        k_matmul<<<n, dim3(F), 0, stream>>>(layer_in, Ws[l], bufB, n);
        // agg = selfloop(M) then += edge messages   (into bufA)
        k_selfloop<<<gNF4, blk, 0, stream>>>((const float4*)bufB, dinv, (float4*)bufA, n);
        k_scatter <<<gE32, blk, 0, stream>>>(bufB, src, dst, dinv, bufA, e);
        // h = relu(agg + b) in place
        k_bias_relu<<<gNF4, blk, 0, stream>>>((float4*)bufA, (const float4*)bs[l], n);
        layer_in = bufA;
    }

    // pooled = mean(h3, axis=0); out = pooled @ fc_w + fc_b
    k_zero128<<<1, dim3(F), 0, stream>>>(pooled);
    k_pool   <<<512, blk, 0, stream>>>(bufA, pooled, n, 1.0f / (float)n);
    k_fc     <<<1, dim3(F), 0, stream>>>(pooled, fcw, fcb, out);
}